// Round 1
// baseline (10937.399 us; speedup 1.0000x reference)
//
#include <hip/hip_runtime.h>

#define D_DYN   3
#define T_STEPS 365
#define B_SZ    1024
#define H_SZ    256
#define NGRP    64      // groups (16 batch rows each)
#define GBLK    4       // blocks per group (64 state cols each)
#define ROWS    16      // batch rows per group

typedef __attribute__((ext_vector_type(8))) short short8;   // 8 bf16 = 4 VGPRs
typedef __attribute__((ext_vector_type(4))) float f32x4;

__device__ __forceinline__ float fast_sigmoid(float x) {
    return __builtin_amdgcn_rcpf(1.0f + __builtin_amdgcn_exp2f(-1.44269504f * x));
}
__device__ __forceinline__ float fast_tanh(float x) {
    return 2.0f * __builtin_amdgcn_rcpf(1.0f + __builtin_amdgcn_exp2f(-2.88539008f * x)) - 1.0f;
}
__device__ __forceinline__ unsigned short f2bf(float x) {   // fp32 -> bf16 RTNE
    unsigned int u = __float_as_uint(x);
    u = (u + 0x7FFFu + ((u >> 16) & 1u)) >> 16;
    return (unsigned short)u;
}

// Grid: 256 blocks x 256 threads. blockIdx = j*64 + g  (j = block-in-group,
// g = group) so a group's 4 blocks share blockIdx%8 -> same XCD (perf only).
__global__ void __launch_bounds__(256)
ealstm_main(const float* __restrict__ x_dyn, const float* __restrict__ x_stat,
            const float* __restrict__ w_i, const float* __restrict__ b_i,
            const float* __restrict__ w_f, const float* __restrict__ b_f,
            const float* __restrict__ w_g, const float* __restrict__ b_g,
            const float* __restrict__ w_o, const float* __restrict__ b_o,
            const float* __restrict__ w_head,
            unsigned int* __restrict__ cnt, unsigned short* __restrict__ h_glob,
            float* __restrict__ partials)
{
    const int tid  = threadIdx.x;
    const int lane = tid & 63;
    const int wv   = tid >> 6;         // wave 0..3
    const int l16  = lane >> 4;        // 0..3
    const int j    = blockIdx.x >> 6;  // block-in-group 0..3
    const int g    = blockIdx.x & 63;  // group 0..63
    const int rb   = g * ROWS;                    // batch row base
    const int col  = (wv << 4) + (lane & 15);     // 0..63 within block's col slice
    const int colH = j * 64 + col;                // absolute state column

    __shared__ float          x_lds[ROWS * 3];
    __shared__ unsigned short h_packed[8 * 64 * 8];   // 8 KB: [kt][lane][elem] A-frag layout
    __shared__ float          red[4][ROWS];

    // ---- load Wh slice into registers as bf16 B-fragments (one-time) ----
    // B-frag assumed map: lane holds B[k = kt*32 + (lane>>4)*8 + e][col = n0 + (lane&15)]
    // A uses the SAME (lane,e)->k map, so any bijective HW k-permutation cancels.
    short8 wf[8], wg[8], wo[8];
#pragma unroll
    for (int kt = 0; kt < 8; ++kt) {
        short8 af, ag, ao;
#pragma unroll
        for (int e = 0; e < 8; ++e) {
            const int krow = 3 + kt * 32 + l16 * 8 + e;   // Wh = W[3:]
            af[e] = (short)f2bf(w_f[krow * H_SZ + colH]);
            ag[e] = (short)f2bf(w_g[krow * H_SZ + colH]);
            ao[e] = (short)f2bf(w_o[krow * H_SZ + colH]);
        }
        wf[kt] = af; wg[kt] = ag; wo[kt] = ao;
    }
    // Wx rows (0..2), biases, head weight, w_i -- all per-lane scalars
    float wxf[3], wxg[3], wxo[3], wif[3];
#pragma unroll
    for (int d = 0; d < 3; ++d) {
        wxf[d] = w_f[d * H_SZ + colH];
        wxg[d] = w_g[d * H_SZ + colH];
        wxo[d] = w_o[d * H_SZ + colH];
        wif[d] = w_i[d * H_SZ + colH];
    }
    const float bfv = b_f[colH], bgv = b_g[colH], bov = b_o[colH], biv = b_i[colH];
    const float whd = w_head[colH];

    const int xrow = tid / 3, xd = tid - xrow * 3;   // used when tid < 48

    // ---- static input gate i = sigmoid(x_stat @ w_i + b_i) ----
    if (tid < ROWS * 3) x_lds[tid] = x_stat[(rb + xrow) * 3 + xd];
    __syncthreads();
    float iv[4], cst[4], hq[4];
#pragma unroll
    for (int q = 0; q < 4; ++q) {
        const int r = l16 * 4 + q;
        float z = biv;
#pragma unroll
        for (int d = 0; d < 3; ++d) z += x_lds[r * 3 + d] * wif[d];
        iv[q]  = fast_sigmoid(z);
        cst[q] = 0.0f;
        hq[q]  = 0.0f;
    }
    __syncthreads();

    unsigned int* const my_cnt = cnt + g * 32;   // 128B-padded counters

    for (int t = 0; t < T_STEPS; ++t) {
        // stage x_t (48 floats)
        if (tid < ROWS * 3)
            x_lds[tid] = x_dyn[((rb + xrow) * T_STEPS + t) * D_DYN + xd];

        // wait for all 4 blocks of the group to have published h^{t-1}
        if (t > 0 && tid == 0) {
            const unsigned int target = (unsigned int)(GBLK * t);
            int guard = 0;
            while (__hip_atomic_load(my_cnt, __ATOMIC_ACQUIRE, __HIP_MEMORY_SCOPE_AGENT) < target) {
                __builtin_amdgcn_s_sleep(2);
                if (++guard > (1 << 19)) break;   // bounded: wrong answer > hang
            }
        }
        __syncthreads();

        // h^{t-1} -> LDS (already in packed A-fragment order in global)
        uint4* const d4 = (uint4*)h_packed;
        if (t > 0) {
            const uint4* s4 = (const uint4*)(h_glob + (((unsigned)((t - 1) & 1)) * NGRP + g) * 4096);
            d4[tid * 2]     = s4[tid * 2];
            d4[tid * 2 + 1] = s4[tid * 2 + 1];
        } else {
            uint4 z4; z4.x = 0; z4.y = 0; z4.z = 0; z4.w = 0;
            d4[tid * 2]     = z4;
            d4[tid * 2 + 1] = z4;
        }

        // z_x + bias -> accumulator C-in (C/D layout: col=lane&15, row=(lane>>4)*4+q)
        f32x4 accf, accg, acco;
#pragma unroll
        for (int q = 0; q < 4; ++q) {
            const int r = l16 * 4 + q;
            const float x0 = x_lds[r * 3 + 0], x1 = x_lds[r * 3 + 1], x2 = x_lds[r * 3 + 2];
            accf[q] = bfv + x0 * wxf[0] + x1 * wxf[1] + x2 * wxf[2];
            accg[q] = bgv + x0 * wxg[0] + x1 * wxg[1] + x2 * wxg[2];
            acco[q] = bov + x0 * wxo[0] + x1 * wxo[1] + x2 * wxo[2];
        }
        __syncthreads();   // h_packed ready

        // z += h @ Wh : 8 k-tiles x 3 gates
        const short8* hp = (const short8*)h_packed;
#pragma unroll
        for (int kt = 0; kt < 8; ++kt) {
            const short8 a = hp[kt * 64 + lane];
            accf = __builtin_amdgcn_mfma_f32_16x16x32_bf16(a, wf[kt], accf, 0, 0, 0);
            accg = __builtin_amdgcn_mfma_f32_16x16x32_bf16(a, wg[kt], accg, 0, 0, 0);
            acco = __builtin_amdgcn_mfma_f32_16x16x32_bf16(a, wo[kt], acco, 0, 0, 0);
        }

        // gates + state update (fp32)
#pragma unroll
        for (int q = 0; q < 4; ++q) {
            const float fq = fast_sigmoid(accf[q]);
            const float gq = fast_tanh(accg[q]);
            const float oq = fast_sigmoid(acco[q]);
            const float cq = fq * cst[q] + iv[q] * gq;
            cst[q] = cq;
            hq[q]  = oq * fast_tanh(cq);
        }

        if (t < T_STEPS - 1) {
            // publish own 16x64 h-slice, bf16, in packed A-frag order
            unsigned short* dst = h_glob + (((unsigned)(t & 1)) * NGRP + g) * 4096;
            const int kt   = 2 * j + (col >> 5);
            const int lnpb = 16 * ((col >> 3) & 3);
            const int elem = col & 7;
#pragma unroll
            for (int q = 0; q < 4; ++q) {
                const int r = l16 * 4 + q;
                dst[(kt * 64 + (r + lnpb)) * 8 + elem] = f2bf(hq[q]);
            }
            __threadfence();            // per-writer agent fence
            __syncthreads();            // all stores drained before signal
            if (tid == 0)
                __hip_atomic_fetch_add(my_cnt, 1u, __ATOMIC_RELEASE, __HIP_MEMORY_SCOPE_AGENT);
        }
    }

    // ---- head partials: p[r] = sum_{own 64 cols} h[r][c] * w_head[c] ----
    float p[4];
#pragma unroll
    for (int q = 0; q < 4; ++q) p[q] = hq[q] * whd;
#pragma unroll
    for (int off = 1; off < 16; off <<= 1) {
#pragma unroll
        for (int q = 0; q < 4; ++q) p[q] += __shfl_xor(p[q], off, 64);
    }
    if ((lane & 15) == 0) {
#pragma unroll
        for (int q = 0; q < 4; ++q) red[wv][l16 * 4 + q] = p[q];
    }
    __syncthreads();
    if (tid < ROWS) {
        const float s = red[0][tid] + red[1][tid] + red[2][tid] + red[3][tid];
        partials[(rb + tid) * 4 + j] = s;
    }
}

// deterministic 4-way reduce + bias (avoids float atomics on d_out)
__global__ void __launch_bounds__(256)
ealstm_reduce(const float* __restrict__ partials, const float* __restrict__ b_head,
              float* __restrict__ out)
{
    const int b = blockIdx.x * 256 + threadIdx.x;
    if (b < B_SZ)
        out[b] = partials[b * 4 + 0] + partials[b * 4 + 1]
               + partials[b * 4 + 2] + partials[b * 4 + 3] + b_head[0];
}

extern "C" void kernel_launch(void* const* d_in, const int* in_sizes, int n_in,
                              void* d_out, int out_size, void* d_ws, size_t ws_size,
                              hipStream_t stream)
{
    const float* x_dyn  = (const float*)d_in[0];
    const float* x_stat = (const float*)d_in[1];
    const float* w_i    = (const float*)d_in[2];
    const float* b_i    = (const float*)d_in[3];
    const float* w_f    = (const float*)d_in[4];
    const float* b_f    = (const float*)d_in[5];
    const float* w_g    = (const float*)d_in[6];
    const float* b_g    = (const float*)d_in[7];
    const float* w_o    = (const float*)d_in[8];
    const float* b_o    = (const float*)d_in[9];
    const float* w_head = (const float*)d_in[10];
    const float* b_head = (const float*)d_in[11];

    unsigned char* ws = (unsigned char*)d_ws;
    unsigned int*   cnt      = (unsigned int*)ws;                        // 8 KB (64 x 128B)
    unsigned short* h_glob   = (unsigned short*)(ws + 8192);             // 1 MB (2 x 64 x 8KB)
    float*          partials = (float*)(ws + 8192 + 2 * NGRP * 8192);    // 16 KB

    hipMemsetAsync(cnt, 0, 8192, stream);   // counters must be zero every call
    ealstm_main<<<dim3(256), dim3(256), 0, stream>>>(
        x_dyn, x_stat, w_i, b_i, w_f, b_f, w_g, b_g, w_o, b_o, w_head,
        cnt, h_glob, partials);
    ealstm_reduce<<<dim3(4), dim3(256), 0, stream>>>(partials, b_head, (float*)d_out);
}

// Round 2
// 1156.514 us; speedup vs baseline: 9.4572x; 9.4572x over previous
//
#include <hip/hip_runtime.h>

#define T_STEPS 365
#define H_SZ    256
#define ROWS    16
#define XLEN    (T_STEPS * 3)   // 1095 floats per row (odd stride -> benign banks)

typedef __attribute__((ext_vector_type(8))) short short8;   // 8 bf16 = 4 VGPRs
typedef __attribute__((ext_vector_type(4))) float f32x4;

__device__ __forceinline__ float fast_sigmoid(float x) {
    return __builtin_amdgcn_rcpf(1.0f + __builtin_amdgcn_exp2f(-1.44269504f * x));
}
__device__ __forceinline__ float fast_tanh(float x) {
    return 2.0f * __builtin_amdgcn_rcpf(1.0f + __builtin_amdgcn_exp2f(-2.88539008f * x)) - 1.0f;
}
__device__ __forceinline__ unsigned short f2bf(float x) {   // fp32 -> bf16 RTNE
    unsigned int u = __float_as_uint(x);
    u = (u + 0x7FFFu + ((u >> 16) & 1u)) >> 16;
    return (unsigned short)u;
}

// One block = 16 waves = one batch-group of 16 rows, ALL 256 state cols.
// Wave w owns state cols [16w,16w+16); holds Wh B-frags (3 gates x 8 kt) in
// VGPRs (96/lane). h exchanged via LDS double buffer, 1 barrier/step.
// No inter-block communication anywhere.
__global__ void __launch_bounds__(1024, 4)
ealstm_fused(const float* __restrict__ x_dyn, const float* __restrict__ x_stat,
             const float* __restrict__ w_i, const float* __restrict__ b_i,
             const float* __restrict__ w_f, const float* __restrict__ b_f,
             const float* __restrict__ w_g, const float* __restrict__ b_g,
             const float* __restrict__ w_o, const float* __restrict__ b_o,
             const float* __restrict__ w_head, const float* __restrict__ b_head,
             float* __restrict__ out)
{
    const int tid  = threadIdx.x;
    const int lane = tid & 63;
    const int wv   = tid >> 6;        // wave 0..15
    const int m    = lane & 15;
    const int l16  = lane >> 4;       // 0..3
    const int rb   = blockIdx.x * ROWS;
    const int c    = wv * 16 + m;     // this lane's state column (0..255)

    __shared__ unsigned short hbuf[2][4096];       // 2 x 8 KB, A-frag packed
    __shared__ float          coef[3 * H_SZ][4];   // {wx0,wx1,wx2,b} per gate-col, 12 KB
    __shared__ float          xall[ROWS][XLEN];    // whole x_dyn slice, 70 KB
    __shared__ float          red[16][ROWS];       // x_stat staging + head reduce

    // ---- one-time staging ----
    for (int idx = tid; idx < 3 * H_SZ; idx += 1024) {
        const int gate = idx >> 8, cc = idx & 255;
        const float* wsrc = gate == 0 ? w_f : (gate == 1 ? w_g : w_o);
        const float* bsrc = gate == 0 ? b_f : (gate == 1 ? b_g : b_o);
        coef[idx][0] = wsrc[cc];
        coef[idx][1] = wsrc[H_SZ + cc];
        coef[idx][2] = wsrc[2 * H_SZ + cc];
        coef[idx][3] = bsrc[cc];
    }
#pragma unroll 1
    for (int r = 0; r < ROWS; ++r) {
        const float* src = x_dyn + (size_t)(rb + r) * XLEN;
        for (int idx = tid; idx < XLEN; idx += 1024) xall[r][idx] = src[idx];
    }
    ((unsigned int*)hbuf[0])[2 * tid]     = 0u;    // zero h^{-1}
    ((unsigned int*)hbuf[0])[2 * tid + 1] = 0u;
    if (tid < ROWS * 3) ((float*)red)[tid] = x_stat[rb * 3 + tid];

    // ---- Wh slice -> bf16 B-fragments in registers ----
    // B map: lane holds B[k = kt*32 + l16*8 + e][col = c]; A uses the same
    // (lane,e)->k map so any bijective HW k-permutation cancels.
    short8 wfr[8], wgr[8], wor[8];
#pragma unroll
    for (int kt = 0; kt < 8; ++kt) {
        short8 af, ag, ao;
#pragma unroll
        for (int e = 0; e < 8; ++e) {
            const int off = (3 + kt * 32 + l16 * 8 + e) * H_SZ + c;
            af[e] = (short)f2bf(w_f[off]);
            ag[e] = (short)f2bf(w_g[off]);
            ao[e] = (short)f2bf(w_o[off]);
        }
        wfr[kt] = af; wgr[kt] = ag; wor[kt] = ao;
    }

    __syncthreads();

    // ---- static input gate ----
    float iv[4], cst[4], hq[4];
    {
        const float bi  = b_i[c];
        const float wi0 = w_i[c], wi1 = w_i[H_SZ + c], wi2 = w_i[2 * H_SZ + c];
        const float* xs = (const float*)red;
#pragma unroll
        for (int q = 0; q < 4; ++q) {
            const int r = l16 * 4 + q;
            iv[q] = fast_sigmoid(bi + xs[r * 3] * wi0 + xs[r * 3 + 1] * wi1 + xs[r * 3 + 2] * wi2);
            cst[q] = 0.0f; hq[q] = 0.0f;
        }
    }

    // h-write base: value h[r][c] goes to A-pack slot for k=c:
    // kt=c>>5, k'=c&31, slot=r+16*(k'>>3), e=k'&7  (verified layout, round 1)
    const int hwbase = (((wv >> 1) * 64 + 16 * ((wv & 1) * 2 + (m >> 3)) + l16 * 4) << 3) + (m & 7);

    const f32x4* cf4 = (const f32x4*)coef;

    for (int t = 0; t < T_STEPS; ++t) {
        const int cur = t & 1;

        // z = x_t @ Wx + b  (acc C-in; C/D: col=lane&15, row=l16*4+q)
        const f32x4 cff = cf4[c];
        const f32x4 cfg = cf4[H_SZ + c];
        const f32x4 cfo = cf4[2 * H_SZ + c];
        f32x4 accf, accg, acco;
#pragma unroll
        for (int q = 0; q < 4; ++q) {
            const float* xr = &xall[l16 * 4 + q][t * 3];
            const float x0 = xr[0], x1 = xr[1], x2 = xr[2];
            accf[q] = cff[3] + x0 * cff[0] + x1 * cff[1] + x2 * cff[2];
            accg[q] = cfg[3] + x0 * cfg[0] + x1 * cfg[1] + x2 * cfg[2];
            acco[q] = cfo[3] + x0 * cfo[0] + x1 * cfo[1] + x2 * cfo[2];
        }

        // z += h @ Wh
        const short8* ap = (const short8*)hbuf[cur];
#pragma unroll
        for (int kt = 0; kt < 8; ++kt) {
            const short8 a = ap[kt * 64 + lane];
            accf = __builtin_amdgcn_mfma_f32_16x16x32_bf16(a, wfr[kt], accf, 0, 0, 0);
            accg = __builtin_amdgcn_mfma_f32_16x16x32_bf16(a, wgr[kt], accg, 0, 0, 0);
            acco = __builtin_amdgcn_mfma_f32_16x16x32_bf16(a, wor[kt], acco, 0, 0, 0);
        }

        // gates + state
#pragma unroll
        for (int q = 0; q < 4; ++q) {
            const float fq = fast_sigmoid(accf[q]);
            const float gq = fast_tanh(accg[q]);
            const float oq = fast_sigmoid(acco[q]);
            const float cq = fq * cst[q] + iv[q] * gq;
            cst[q] = cq;
            hq[q]  = oq * fast_tanh(cq);
        }

        if (t < T_STEPS - 1) {
            unsigned short* hw = hbuf[cur ^ 1] + hwbase;
#pragma unroll
            for (int q = 0; q < 4; ++q) hw[q * 8] = f2bf(hq[q]);
        }
        __syncthreads();   // step t writes (buf cur^1) visible before step t+1 reads
    }

    // ---- head: out[r] = sum_c h[r][c]*w_head[c] + b_head ----
    float p[4];
    const float whd = w_head[c];
#pragma unroll
    for (int q = 0; q < 4; ++q) p[q] = hq[q] * whd;
#pragma unroll
    for (int off = 1; off < 16; off <<= 1) {
#pragma unroll
        for (int q = 0; q < 4; ++q) p[q] += __shfl_xor(p[q], off, 64);
    }
    if (m == 0) {
#pragma unroll
        for (int q = 0; q < 4; ++q) red[wv][l16 * 4 + q] = p[q];
    }
    __syncthreads();
    if (tid < ROWS) {
        float s = b_head[0];
#pragma unroll
        for (int ww = 0; ww < 16; ++ww) s += red[ww][tid];
        out[rb + tid] = s;
    }
}

extern "C" void kernel_launch(void* const* d_in, const int* in_sizes, int n_in,
                              void* d_out, int out_size, void* d_ws, size_t ws_size,
                              hipStream_t stream)
{
    const float* x_dyn  = (const float*)d_in[0];
    const float* x_stat = (const float*)d_in[1];
    const float* w_i    = (const float*)d_in[2];
    const float* b_i    = (const float*)d_in[3];
    const float* w_f    = (const float*)d_in[4];
    const float* b_f    = (const float*)d_in[5];
    const float* w_g    = (const float*)d_in[6];
    const float* b_g    = (const float*)d_in[7];
    const float* w_o    = (const float*)d_in[8];
    const float* b_o    = (const float*)d_in[9];
    const float* w_head = (const float*)d_in[10];
    const float* b_head = (const float*)d_in[11];

    ealstm_fused<<<dim3(64), dim3(1024), 0, stream>>>(
        x_dyn, x_stat, w_i, b_i, w_f, b_f, w_g, b_g, w_o, b_o,
        w_head, b_head, (float*)d_out);
}

// Round 4
// 973.350 us; speedup vs baseline: 11.2369x; 1.1882x over previous
//
#include <hip/hip_runtime.h>

#define T_STEPS 365
#define XLEN    (T_STEPS * 3)
#define H_SZ    256
#define ROWS    16
#define NW      8      // waves per block
#define CPW     32     // state cols per wave

typedef __attribute__((ext_vector_type(8))) short bf16x8;   // 8 bf16
typedef __attribute__((ext_vector_type(4))) short bf16x4;   // 4 bf16
typedef __attribute__((ext_vector_type(4))) float f32x4;

__device__ __forceinline__ float fast_sigmoid(float x) {
    return __builtin_amdgcn_rcpf(1.0f + __builtin_amdgcn_exp2f(-1.44269504f * x));
}
__device__ __forceinline__ float fast_tanh(float x) {
    return 2.0f * __builtin_amdgcn_rcpf(1.0f + __builtin_amdgcn_exp2f(-2.88539008f * x)) - 1.0f;
}
__device__ __forceinline__ unsigned short f2bf(float x) {   // fp32 -> bf16 RTNE
    unsigned int u = __float_as_uint(x);
    u = (u + 0x7FFFu + ((u >> 16) & 1u)) >> 16;
    return (unsigned short)u;
}

// One block = 8 waves = 16 batch rows x all 256 state cols.
// Transposed MFMA: D[c][r] = sum_k W^T[c][k] * hx^T[k][r].
//   A (weights, incl. Wx+bias as kt=0) lives in VGPRs: 54 frags/lane.
//   B (h^T) packed in LDS double buffer; kt0 B-frag (x_t,1) prepacked for all t.
// Lane owns (r = lane&15, c = wbase + ct*16 + (lane>>4)*4 + q) -> 4 consecutive
// c per (ct) -> h-write is one ds_write_b64 per ct. 1 barrier/step.
__global__ void __launch_bounds__(512, 2)
ealstm_fused(const float* __restrict__ x_dyn, const float* __restrict__ x_stat,
             const float* __restrict__ w_i, const float* __restrict__ b_i,
             const float* __restrict__ w_f, const float* __restrict__ b_f,
             const float* __restrict__ w_g, const float* __restrict__ b_g,
             const float* __restrict__ w_o, const float* __restrict__ b_o,
             const float* __restrict__ w_head, const float* __restrict__ b_head,
             float* __restrict__ out)
{
    const int tid   = threadIdx.x;
    const int lane  = tid & 63;
    const int wv    = tid >> 6;       // 0..7
    const int m     = lane & 15;      // batch row this lane owns (N dim)
    const int l16   = lane >> 4;      // 0..3
    const int rb    = blockIdx.x * ROWS;
    const int wbase = wv * CPW;

    __shared__ unsigned short hbuf[2][4096];       // [buf][kt][L][e] = 2 x 8 KB
    __shared__ unsigned short xpack[T_STEPS][64];  // [t][r*4+e] = {x0,x1,x2,1}, 46.7 KB
    __shared__ float          red[NW][ROWS];

    // ---- one-time: pack x_dyn (bf16) + the constant 1.0 for bias row ----
    for (int idx = tid; idx < T_STEPS * ROWS; idx += 512) {
        const int t = idx % T_STEPS, r = idx / T_STEPS;
        const float* s = x_dyn + (size_t)(rb + r) * XLEN + t * 3;
        bf16x4 pk;
        pk[0] = (short)f2bf(s[0]); pk[1] = (short)f2bf(s[1]);
        pk[2] = (short)f2bf(s[2]); pk[3] = (short)0x3F80;      // 1.0 bf16
        *(bf16x4*)&xpack[t][r * 4] = pk;
    }
    for (int idx = tid; idx < 2048; idx += 512) ((unsigned int*)hbuf[0])[idx] = 0u;

    // ---- one-time: weight A-frags in registers ----
    // A map: lane holds A[c = cbase + (lane&15)][k' = (lane>>4)*8 + e].
    // kt=0 is the x-block: k'=0..2 -> Wx rows, k'=3 -> bias, else 0.
    const float* wsrc[3] = {w_f, w_g, w_o};
    const float* bsrc[3] = {b_f, b_g, b_o};
    bf16x8 wA[9][2][3];
#pragma unroll
    for (int ct = 0; ct < 2; ++ct) {
        const int c = wbase + ct * 16 + m;
#pragma unroll
        for (int g = 0; g < 3; ++g) {
            bf16x8 a0 = (bf16x8)0;
            if (l16 == 0) {
                a0[0] = (short)f2bf(wsrc[g][0 * H_SZ + c]);
                a0[1] = (short)f2bf(wsrc[g][1 * H_SZ + c]);
                a0[2] = (short)f2bf(wsrc[g][2 * H_SZ + c]);
                a0[3] = (short)f2bf(bsrc[g][c]);
            }
            wA[0][ct][g] = a0;
#pragma unroll
            for (int kt = 1; kt <= 8; ++kt) {
                bf16x8 a;
#pragma unroll
                for (int e = 0; e < 8; ++e)
                    a[e] = (short)f2bf(wsrc[g][(3 + (kt - 1) * 32 + l16 * 8 + e) * H_SZ + c]);
                wA[kt][ct][g] = a;
            }
        }
    }

    // ---- static input gate iv + states; head weights ----
    float iv[2][4], cst[2][4], hq[2][4], whd[2][4];
    {
        const float xs0 = x_stat[(rb + m) * 3 + 0];
        const float xs1 = x_stat[(rb + m) * 3 + 1];
        const float xs2 = x_stat[(rb + m) * 3 + 2];
#pragma unroll
        for (int ct = 0; ct < 2; ++ct)
#pragma unroll
            for (int q = 0; q < 4; ++q) {
                const int c = wbase + ct * 16 + l16 * 4 + q;
                iv[ct][q]  = fast_sigmoid(b_i[c] + xs0 * w_i[c] + xs1 * w_i[H_SZ + c]
                                                 + xs2 * w_i[2 * H_SZ + c]);
                cst[ct][q] = 0.0f;
                hq[ct][q]  = 0.0f;
                whd[ct][q] = w_head[c];
            }
    }

    __syncthreads();

    for (int t = 0; t < T_STEPS; ++t) {
        const int cur = t & 1;

        // B-frags: kt0 from xpack (broadcast read + mask), kt1..8 = h^T
        bf16x8 bh[9];
        {
            const bf16x4 v = *(const bf16x4*)&xpack[t][m * 4];
            bf16x8 xf = (bf16x8)0;
            if (l16 == 0) { xf[0] = v[0]; xf[1] = v[1]; xf[2] = v[2]; xf[3] = v[3]; }
            bh[0] = xf;
        }
        const bf16x8* hp = (const bf16x8*)hbuf[cur];
#pragma unroll
        for (int kt = 1; kt <= 8; ++kt) bh[kt] = hp[(kt - 1) * 64 + lane];

        f32x4 acc[2][3] = {};
#pragma unroll
        for (int kt = 0; kt <= 8; ++kt)
#pragma unroll
            for (int ct = 0; ct < 2; ++ct)
#pragma unroll
                for (int g = 0; g < 3; ++g)
                    acc[ct][g] = __builtin_amdgcn_mfma_f32_16x16x32_bf16(
                        wA[kt][ct][g], bh[kt], acc[ct][g], 0, 0, 0);

        // gates + state update; lane's elems: (r=m, c=wbase+ct*16+l16*4+q)
#pragma unroll
        for (int ct = 0; ct < 2; ++ct)
#pragma unroll
            for (int q = 0; q < 4; ++q) {
                const float fq = fast_sigmoid(acc[ct][0][q]);
                const float gq = fast_tanh(acc[ct][1][q]);
                const float oq = fast_sigmoid(acc[ct][2][q]);
                const float cq = fq * cst[ct][q] + iv[ct][q] * gq;
                cst[ct][q] = cq;
                hq[ct][q]  = oq * fast_tanh(cq);
            }

        if (t < T_STEPS - 1) {
            // h[r=m][c0..c0+3] -> B-pack slot (kt=c>>5, L=m+16*((c&31)>>3), e=c&7)
            unsigned short* hw = hbuf[cur ^ 1];
#pragma unroll
            for (int ct = 0; ct < 2; ++ct) {
                const int c0 = wbase + ct * 16 + l16 * 4;
                const int kt = c0 >> 5;
                const int L  = m + 16 * ((c0 & 31) >> 3);
                bf16x4 pk;
#pragma unroll
                for (int q = 0; q < 4; ++q) pk[q] = (short)f2bf(hq[ct][q]);
                *(bf16x4*)&hw[(kt * 64 + L) * 8 + (c0 & 7)] = pk;
            }
        }
        __syncthreads();
    }

    // ---- head: out[r] = sum_c h[r][c] w_head[c] + b_head ----
    float p = 0.0f;
#pragma unroll
    for (int ct = 0; ct < 2; ++ct)
#pragma unroll
        for (int q = 0; q < 4; ++q) p += hq[ct][q] * whd[ct][q];
    p += __shfl_xor(p, 16);
    p += __shfl_xor(p, 32);
    if (lane < 16) red[wv][m] = p;
    __syncthreads();
    if (tid < ROWS) {
        float s = b_head[0];
#pragma unroll
        for (int w = 0; w < NW; ++w) s += red[w][tid];
        out[rb + tid] = s;
    }
}

extern "C" void kernel_launch(void* const* d_in, const int* in_sizes, int n_in,
                              void* d_out, int out_size, void* d_ws, size_t ws_size,
                              hipStream_t stream)
{
    const float* x_dyn  = (const float*)d_in[0];
    const float* x_stat = (const float*)d_in[1];
    const float* w_i    = (const float*)d_in[2];
    const float* b_i    = (const float*)d_in[3];
    const float* w_f    = (const float*)d_in[4];
    const float* b_f    = (const float*)d_in[5];
    const float* w_g    = (const float*)d_in[6];
    const float* b_g    = (const float*)d_in[7];
    const float* w_o    = (const float*)d_in[8];
    const float* b_o    = (const float*)d_in[9];
    const float* w_head = (const float*)d_in[10];
    const float* b_head = (const float*)d_in[11];

    ealstm_fused<<<dim3(64), dim3(512), 0, stream>>>(
        x_dyn, x_stat, w_i, b_i, w_f, b_f, w_g, b_g, w_o, b_o,
        w_head, b_head, (float*)d_out);
}